// Round 1
// baseline (188.035 us; speedup 1.0000x reference)
//
#include <hip/hip_runtime.h>
#include <stdint.h>

#define NQ     8192           // points per batch
#define NB     2
#define KNN    10
#define NCHUNK 16
#define CHUNK  (NQ / NCHUNK)  // 512
#define NTOT   (NB * NQ)      // 16384 queries
#define IDXMASK 0x1FFFu

static __device__ __forceinline__ uint32_t umin32(uint32_t a, uint32_t b) { return a < b ? a : b; }
static __device__ __forceinline__ uint32_t umax32(uint32_t a, uint32_t b) { return a > b ? a : b; }

// Kernel 1: per-chunk partial top-10 per query.
// grid (256, 4), block 256. wave w of block handles chunk blockIdx.y*4+w.
// lane = query within the 64-query group blockIdx.x.
__global__ __launch_bounds__(256) void knn_partial_kernel(
    const float* __restrict__ p1, uint32_t* __restrict__ lists)
{
    const int lane = threadIdx.x & 63;
    const int wave = threadIdx.x >> 6;
    const int qid  = blockIdx.x * 64 + lane;                        // 0..16383
    const int b    = __builtin_amdgcn_readfirstlane(blockIdx.x >> 7);
    const int qi   = qid & (NQ - 1);
    const int chunk = __builtin_amdgcn_readfirstlane(blockIdx.y * 4 + wave);

    const float* __restrict__ P = p1 + (size_t)b * NQ * 3;
    const float qx = P[qi * 3 + 0];
    const float qy = P[qi * 3 + 1];
    const float qz = P[qi * 3 + 2];

    uint32_t l[KNN];
#pragma unroll
    for (int s = 0; s < KNN; ++s) l[s] = 0xFFFFFFFFu;

    const int j0 = chunk * CHUNK;
#pragma unroll 4
    for (int t = 0; t < CHUNK; ++t) {
        const int j = j0 + t;
        const float cx = P[j * 3 + 0];   // uniform address -> s_load broadcast
        const float cy = P[j * 3 + 1];
        const float cz = P[j * 3 + 2];
        const float dx = qx - cx, dy = qy - cy, dz = qz - cz;
        const float d  = dx * dx + dy * dy + dz * dz;
        uint32_t key = (__float_as_uint(d) & ~IDXMASK) | (uint32_t)j;
        key = (j == qi) ? 0xFFFFFFFFu : key;     // exclude self
        // branchless sorted insert (ascending): 10x min/max bubble
#pragma unroll
        for (int s = 0; s < KNN; ++s) {
            const uint32_t lo = umin32(key, l[s]);
            key  = umax32(key, l[s]);
            l[s] = lo;
        }
    }

    uint32_t* __restrict__ dst = lists + ((size_t)qid * NCHUNK + chunk) * KNN;
#pragma unroll
    for (int s = 0; s < KNN; ++s) dst[s] = l[s];
}

// Kernel 2: merge 16 partial lists per query, gather neighbors, Laplacian L1 loss.
__global__ __launch_bounds__(256) void knn_merge_loss_kernel(
    const float* __restrict__ p1, const float* __restrict__ p2,
    const uint32_t* __restrict__ lists, float* __restrict__ out)
{
    const int qid = blockIdx.x * 256 + threadIdx.x;   // 0..16383
    const int b   = qid >> 13;
    const int qi  = qid & (NQ - 1);
    const float* __restrict__ P1 = p1 + (size_t)b * NQ * 3;
    const float* __restrict__ P2 = p2 + (size_t)b * NQ * 3;

    uint32_t l[KNN];
#pragma unroll
    for (int s = 0; s < KNN; ++s) l[s] = 0xFFFFFFFFu;

    const uint32_t* __restrict__ src = lists + (size_t)qid * NCHUNK * KNN; // 160 u32
#pragma unroll 4
    for (int e = 0; e < NCHUNK * KNN; e += 4) {
        const uint4 v = *(const uint4*)(src + e);
        uint32_t k0 = v.x, k1 = v.y, k2 = v.z, k3 = v.w;
#pragma unroll
        for (int s = 0; s < KNN; ++s) { const uint32_t lo = umin32(k0, l[s]); k0 = umax32(k0, l[s]); l[s] = lo; }
#pragma unroll
        for (int s = 0; s < KNN; ++s) { const uint32_t lo = umin32(k1, l[s]); k1 = umax32(k1, l[s]); l[s] = lo; }
#pragma unroll
        for (int s = 0; s < KNN; ++s) { const uint32_t lo = umin32(k2, l[s]); k2 = umax32(k2, l[s]); l[s] = lo; }
#pragma unroll
        for (int s = 0; s < KNN; ++s) { const uint32_t lo = umin32(k3, l[s]); k3 = umax32(k3, l[s]); l[s] = lo; }
    }

    float s1x = 0.f, s1y = 0.f, s1z = 0.f, s2x = 0.f, s2y = 0.f, s2z = 0.f;
#pragma unroll
    for (int s = 0; s < KNN; ++s) {
        const int n = (int)(l[s] & IDXMASK);
        s1x += P1[n * 3 + 0]; s1y += P1[n * 3 + 1]; s1z += P1[n * 3 + 2];
        s2x += P2[n * 3 + 0]; s2y += P2[n * 3 + 1]; s2z += P2[n * 3 + 2];
    }
    const float invk = 1.0f / (float)KNN;
    const float lx = (s1x * invk - P1[qi * 3 + 0]) - (s2x * invk - P2[qi * 3 + 0]);
    const float ly = (s1y * invk - P1[qi * 3 + 1]) - (s2y * invk - P2[qi * 3 + 1]);
    const float lz = (s1z * invk - P1[qi * 3 + 2]) - (s2z * invk - P2[qi * 3 + 2]);
    float acc = fabsf(lx) + fabsf(ly) + fabsf(lz);

    // wave reduction (64 lanes)
#pragma unroll
    for (int off = 32; off > 0; off >>= 1)
        acc += __shfl_down(acc, off, 64);

    if ((threadIdx.x & 63) == 0) {
        const float scale = 1.0f / (float)(NB * NQ * 3);
        atomicAdd(out, acc * scale);
    }
}

extern "C" void kernel_launch(void* const* d_in, const int* in_sizes, int n_in,
                              void* d_out, int out_size, void* d_ws, size_t ws_size,
                              hipStream_t stream) {
    const float* p1 = (const float*)d_in[0];
    const float* p2 = (const float*)d_in[1];
    float* out      = (float*)d_out;
    uint32_t* lists = (uint32_t*)d_ws;   // 16384 * 16 * 10 * 4 B = 10.5 MB

    hipMemsetAsync(d_out, 0, sizeof(float), stream);

    dim3 g1(NTOT / 64, NCHUNK / 4);
    knn_partial_kernel<<<g1, dim3(256), 0, stream>>>(p1, lists);
    knn_merge_loss_kernel<<<dim3(NTOT / 256), dim3(256), 0, stream>>>(p1, p2, lists, out);
}

// Round 2
// 174.474 us; speedup vs baseline: 1.0777x; 1.0777x over previous
//
#include <hip/hip_runtime.h>
#include <stdint.h>

#define NQ 8192
#define NB 2
#define KNN 10
#define K1  (KNN + 1)         // keep 11 so self (dist 0) can be dropped at the end
#define NTOT (NB * NQ)
#define IDXMASK 0x1FFFu

static __device__ __forceinline__ uint32_t umin32(uint32_t a, uint32_t b) { return a < b ? a : b; }
static __device__ __forceinline__ uint32_t umax32(uint32_t a, uint32_t b) { return a > b ? a : b; }

// ---------------- Kernel 1: per-chunk partial top-10 (self included) ----------------
// grid (NTOT/64, NC/4), block 256. lane = query; candidate index wave-uniform (scalar loads).
template <int NC>
__global__ __launch_bounds__(256) void knn_partial(
    const float* __restrict__ p1, uint32_t* __restrict__ lists)
{
    constexpr int CH = NQ / NC;
    const int lane  = threadIdx.x & 63;
    const int wave  = threadIdx.x >> 6;
    const int qid   = blockIdx.x * 64 + lane;          // 0..NTOT-1
    const int b     = blockIdx.x >> 7;                 // 128 groups per batch
    const int qi    = qid & (NQ - 1);
    const int chunk = blockIdx.y * 4 + wave;

    const float* __restrict__ P = p1 + (size_t)b * NQ * 3;
    const float qx = P[qi * 3 + 0];
    const float qy = P[qi * 3 + 1];
    const float qz = P[qi * 3 + 2];

    uint32_t l[KNN];
#pragma unroll
    for (int s = 0; s < KNN; ++s) l[s] = 0xFFFFFFFFu;

    const int j0 = chunk * CH;
#pragma unroll 8
    for (int t = 0; t < CH; ++t) {
        const int j = j0 + t;
        const float dx = qx - P[j * 3 + 0];            // wave-uniform addr -> s_load
        const float dy = qy - P[j * 3 + 1];
        const float dz = qz - P[j * 3 + 2];
        const float d  = fmaf(dx, dx, fmaf(dy, dy, dz * dz));
        uint32_t key = (__float_as_uint(d) & ~IDXMASK) | (uint32_t)j;
        // no self-check: self (d=0) is the global min key, dropped in final merge
#pragma unroll
        for (int s = 0; s < KNN; ++s) {
            const uint32_t m = l[s];
            l[s] = umin32(key, m);
            key  = umax32(key, m);
        }
    }

    uint32_t* __restrict__ dst = lists + ((size_t)qid * NC + chunk) * KNN;
#pragma unroll
    for (int s = 0; s < KNN; ++s) dst[s] = l[s];
}

// ---------------- Stage A: 4 threads/query, each merges NC/4 lists -> top-11 ----------------
template <int NC>
__global__ __launch_bounds__(256) void knn_mergeA(
    const uint32_t* __restrict__ lists, uint32_t* __restrict__ ml)
{
    const int t = blockIdx.x * 256 + threadIdx.x;      // 0 .. NTOT*4-1
    const int q = t >> 2;
    const int m = t & 3;
    constexpr int L = NC / 4;

    uint32_t l[K1];
#pragma unroll
    for (int s = 0; s < K1; ++s) l[s] = 0xFFFFFFFFu;

    const uint32_t* __restrict__ src = lists + ((size_t)q * NC + m * L) * KNN;
#pragma unroll 4
    for (int e = 0; e < L * KNN; e += 2) {             // 8B-aligned (KNN*4=40B stride)
        const uint2 v = *(const uint2*)(src + e);
        uint32_t k0 = v.x, k1 = v.y;
#pragma unroll
        for (int s = 0; s < K1; ++s) { const uint32_t mm = l[s]; l[s] = umin32(k0, mm); k0 = umax32(k0, mm); }
#pragma unroll
        for (int s = 0; s < K1; ++s) { const uint32_t mm = l[s]; l[s] = umin32(k1, mm); k1 = umax32(k1, mm); }
    }

    uint32_t* __restrict__ dst = ml + ((size_t)q * 4 + m) * K1;
#pragma unroll
    for (int s = 0; s < K1; ++s) dst[s] = l[s];
}

// ---------------- Final: merge NK keys/query -> top-11, drop self, gather, L1 loss ----------------
template <int NK>
__global__ __launch_bounds__(256) void knn_final(
    const float* __restrict__ p1, const float* __restrict__ p2,
    const uint32_t* __restrict__ keys, float* __restrict__ out)
{
    const int qid = blockIdx.x * 256 + threadIdx.x;    // 0..NTOT-1
    const int b   = qid >> 13;
    const int qi  = qid & (NQ - 1);
    const float* __restrict__ P1 = p1 + (size_t)b * NQ * 3;
    const float* __restrict__ P2 = p2 + (size_t)b * NQ * 3;

    uint32_t l[K1];
#pragma unroll
    for (int s = 0; s < K1; ++s) l[s] = 0xFFFFFFFFu;

    const uint32_t* __restrict__ src = keys + (size_t)qid * NK;
#pragma unroll 4
    for (int e = 0; e < NK; ++e) {
        uint32_t k = src[e];
#pragma unroll
        for (int s = 0; s < K1; ++s) { const uint32_t mm = l[s]; l[s] = umin32(k, mm); k = umax32(k, mm); }
    }
    // l[0] is self (dist 0); neighbors are l[1..10]

    float s1x = 0.f, s1y = 0.f, s1z = 0.f, s2x = 0.f, s2y = 0.f, s2z = 0.f;
#pragma unroll
    for (int s = 1; s < K1; ++s) {
        const int n = (int)(l[s] & IDXMASK);
        s1x += P1[n * 3 + 0]; s1y += P1[n * 3 + 1]; s1z += P1[n * 3 + 2];
        s2x += P2[n * 3 + 0]; s2y += P2[n * 3 + 1]; s2z += P2[n * 3 + 2];
    }
    const float invk = 1.0f / (float)KNN;
    const float lx = (s1x * invk - P1[qi * 3 + 0]) - (s2x * invk - P2[qi * 3 + 0]);
    const float ly = (s1y * invk - P1[qi * 3 + 1]) - (s2y * invk - P2[qi * 3 + 1]);
    const float lz = (s1z * invk - P1[qi * 3 + 2]) - (s2z * invk - P2[qi * 3 + 2]);
    float acc = fabsf(lx) + fabsf(ly) + fabsf(lz);

#pragma unroll
    for (int off = 32; off > 0; off >>= 1)
        acc += __shfl_down(acc, off, 64);

    if ((threadIdx.x & 63) == 0) {
        const float scale = 1.0f / (float)(NB * NQ * 3);
        atomicAdd(out, acc * scale);
    }
}

extern "C" void kernel_launch(void* const* d_in, const int* in_sizes, int n_in,
                              void* d_out, int out_size, void* d_ws, size_t ws_size,
                              hipStream_t stream) {
    const float* p1 = (const float*)d_in[0];
    const float* p2 = (const float*)d_in[1];
    float* out      = (float*)d_out;

    hipMemsetAsync(d_out, 0, sizeof(float), stream);

    const size_t lists32 = (size_t)NTOT * 32 * KNN * 4;   // 21.0 MB
    const size_t lists16 = (size_t)NTOT * 16 * KNN * 4;   // 10.5 MB
    const size_t mlBytes = (size_t)NTOT * 4 * K1 * 4;     // 2.9 MB

    if (ws_size >= lists32 + mlBytes) {
        constexpr int NC = 32;
        uint32_t* lists = (uint32_t*)d_ws;
        uint32_t* ml    = (uint32_t*)((char*)d_ws + lists32);
        knn_partial<NC><<<dim3(NTOT / 64, NC / 4), 256, 0, stream>>>(p1, lists);
        knn_mergeA<NC><<<dim3(NTOT * 4 / 256), 256, 0, stream>>>(lists, ml);
        knn_final<4 * K1><<<dim3(NTOT / 256), 256, 0, stream>>>(p1, p2, ml, out);
    } else if (ws_size >= lists16 + mlBytes) {
        constexpr int NC = 16;
        uint32_t* lists = (uint32_t*)d_ws;
        uint32_t* ml    = (uint32_t*)((char*)d_ws + lists16);
        knn_partial<NC><<<dim3(NTOT / 64, NC / 4), 256, 0, stream>>>(p1, lists);
        knn_mergeA<NC><<<dim3(NTOT * 4 / 256), 256, 0, stream>>>(lists, ml);
        knn_final<4 * K1><<<dim3(NTOT / 256), 256, 0, stream>>>(p1, p2, ml, out);
    } else {
        constexpr int NC = 16;   // direct single-stage merge, 10.5 MB only
        uint32_t* lists = (uint32_t*)d_ws;
        knn_partial<NC><<<dim3(NTOT / 64, NC / 4), 256, 0, stream>>>(p1, lists);
        knn_final<NC * KNN><<<dim3(NTOT / 256), 256, 0, stream>>>(p1, p2, lists, out);
    }
}